// Round 1
// 282.159 us; speedup vs baseline: 1.0046x; 1.0046x over previous
//
#include <hip/hip_runtime.h>
#include <hip/hip_bf16.h>

// Problem: N=64, C=M=128, F=2048
//   scores[n,c,m] = sum_f X[n,c,f]*A[c,m,f];  W = softmax_m(scores)
//   out[n,c,f]    = sum_m W[n,c,m]*X[n,m,f]
// Strategy: bf16 MFMA (fp32 accumulate) for both GEMMs; memory-bound design.

typedef __attribute__((ext_vector_type(8))) short bf16x8;
typedef __attribute__((ext_vector_type(4))) float f32x4;

#define PART_ELEMS (64 * 128 * 128)          // one K-partial of scores (fp32)
#define WOFF_BYTES (4ull * PART_ELEMS * 4ull) // 16 MiB: parts, then W bf16 (2 MiB)

static __device__ __forceinline__ unsigned f2bf_pk(float a, float b) {
    // round-to-nearest-even bf16 pack: low = a, high = b
    unsigned ua = __float_as_uint(a);
    unsigned ub = __float_as_uint(b);
    ua = (ua + 0x7FFFu + ((ua >> 16) & 1u)) >> 16;
    ub = (ub + 0x7FFFu + ((ub >> 16) & 1u)) >> 16;
    return ua | (ub << 16);
}

static __device__ __forceinline__ bf16x8 pack8(float4 x, float4 y) {
    union { bf16x8 v; unsigned u[4]; } r;
    r.u[0] = f2bf_pk(x.x, x.y);
    r.u[1] = f2bf_pk(x.z, x.w);
    r.u[2] = f2bf_pk(y.x, y.y);
    r.u[3] = f2bf_pk(y.z, y.w);
    return r.v;
}

// ---------------- Kernel 1: partial scores (streaming rewrite) -----------
// grid 512 = (c:128) x (K-quarter p:4); block 256 (4 waves)
// Phase 1: stage X[:, c, p*512..+512) as bf16 in LDS (ONE barrier total).
// Phase 2: barrier-free K loop; A streamed global->reg (depth-2 prefetch)
//          ->bf16->MFMA. A has zero reuse, so no LDS staging for it.
// Wave w owns m in [w*32, w*32+32): acc[4 n-tiles][2 m-tiles].
__global__ __launch_bounds__(256, 2) void k_scores(const float* __restrict__ X,
                                                   const float* __restrict__ A,
                                                   float* __restrict__ part) {
    __shared__ short Xt[64 * 520];   // [n][f] bf16, stride 520 (qs=65 ≡ 1 mod 8: uniform banks)

    const int bx = blockIdx.x;
    const int c  = bx >> 2;
    const int p  = bx & 3;
    const int t  = threadIdx.x;
    const int l  = t & 63;
    const int w  = t >> 6;
    const int l15 = l & 15;
    const int lg  = l >> 4;

    // ---- phase 1: X[:, c, p*512 : p*512+512) -> LDS bf16 ----
    {
        const int fo = (t & 63) * 8;   // 0..504, wave reads one contiguous 2KB row
        const int r0 = t >> 6;         // wave id 0..3
#pragma unroll
        for (int h = 0; h < 2; ++h) {
            float4 v[8][2];
#pragma unroll
            for (int j = 0; j < 8; ++j) {
                const float* g = X + ((size_t)(h * 32 + j * 4 + r0) * 128 + c) * 2048
                                   + p * 512 + fo;
                v[j][0] = *(const float4*)g;
                v[j][1] = *(const float4*)(g + 4);
            }
#pragma unroll
            for (int j = 0; j < 8; ++j)
                *(bf16x8*)&Xt[(h * 32 + j * 4 + r0) * 520 + fo] = pack8(v[j][0], v[j][1]);
        }
    }
    __syncthreads();

    // ---- phase 2: stream A, zero barriers ----
    f32x4 acc[4][2];
#pragma unroll
    for (int i = 0; i < 4; ++i)
#pragma unroll
        for (int j = 0; j < 2; ++j) acc[i][j] = (f32x4)0.0f;

    // lane's A row = m = w*32 + jtile*16 + l15; k offset = lg*8 (+ks*32)
    const float* Aw = A + ((size_t)c * 128 + w * 32 + l15) * 2048 + p * 512 + lg * 8;

    float4 pf[2][4];   // depth-2 prefetch: [slot][mtile*2 + half]
#define LOADA(dst, ks) do {                                        \
        dst[0] = *(const float4*)(Aw + (ks) * 32);                 \
        dst[1] = *(const float4*)(Aw + (ks) * 32 + 4);             \
        dst[2] = *(const float4*)(Aw + 16 * 2048 + (ks) * 32);     \
        dst[3] = *(const float4*)(Aw + 16 * 2048 + (ks) * 32 + 4); \
    } while (0)

    LOADA(pf[0], 0);
    LOADA(pf[1], 1);

#pragma unroll
    for (int ks = 0; ks < 16; ++ks) {
        bf16x8 b0 = pack8(pf[ks & 1][0], pf[ks & 1][1]);
        bf16x8 b1 = pack8(pf[ks & 1][2], pf[ks & 1][3]);
        if (ks + 2 < 16) LOADA(pf[ks & 1], ks + 2);

        bf16x8 a[4];
#pragma unroll
        for (int i = 0; i < 4; ++i)
            a[i] = *(const bf16x8*)&Xt[(i * 16 + l15) * 520 + ks * 32 + lg * 8];

#pragma unroll
        for (int i = 0; i < 4; ++i) {
            acc[i][0] = __builtin_amdgcn_mfma_f32_16x16x32_bf16(a[i], b0, acc[i][0], 0, 0, 0);
            acc[i][1] = __builtin_amdgcn_mfma_f32_16x16x32_bf16(a[i], b1, acc[i][1], 0, 0, 0);
        }
    }
#undef LOADA

    float* outp = part + (size_t)p * PART_ELEMS;
#pragma unroll
    for (int i = 0; i < 4; ++i) {
        const int nb = i * 16 + lg * 4;
#pragma unroll
        for (int j = 0; j < 2; ++j) {
            const int m = w * 32 + j * 16 + l15;
#pragma unroll
            for (int r = 0; r < 4; ++r)
                outp[(size_t)(nb + r) * 16384 + c * 128 + m] = acc[i][j][r];
        }
    }
}

// ---------------- Kernel 2: sum partials + softmax -> W (bf16) -----------
// grid 2048 x 256: one wave per (n,c) row of 128 scores
__global__ __launch_bounds__(256) void k_softmax(const float* __restrict__ part,
                                                 unsigned int* __restrict__ Wout) {
    const int t   = threadIdx.x;
    const int l   = t & 63;
    const int row = blockIdx.x * 4 + (t >> 6);   // row = n*128 + c, < 8192

    const float* s = part + (size_t)row * 128 + 2 * l;
    float v0 = 0.f, v1 = 0.f;
#pragma unroll
    for (int p = 0; p < 4; ++p) {
        float2 v = *(const float2*)(s + (size_t)p * PART_ELEMS);
        v0 += v.x; v1 += v.y;
    }
    float mx = fmaxf(v0, v1);
#pragma unroll
    for (int d = 1; d < 64; d <<= 1) mx = fmaxf(mx, __shfl_xor(mx, d, 64));
    float e0 = __expf(v0 - mx), e1 = __expf(v1 - mx);
    float sm = e0 + e1;
#pragma unroll
    for (int d = 1; d < 64; d <<= 1) sm += __shfl_xor(sm, d, 64);
    const float inv = 1.0f / sm;
    Wout[(size_t)row * 64 + l] = f2bf_pk(e0 * inv, e1 * inv);
}

// ---------------- Kernel 3: combine --------------------------------------
// grid 1024 = (n:64) x (f-tile:16); block 256 (4 waves); tile 128c x 128f, K=m=128
__global__ __launch_bounds__(256, 2) void k_combine(const float* __restrict__ X,
                                                    const unsigned short* __restrict__ W,
                                                    float* __restrict__ out) {
    __shared__ short Wl[128 * 136];  // [c][m] bf16, stride 136 (16B-aligned rows)
    __shared__ short T[128 * 40];    // [f][m-chunk(32)] bf16, stride 40

    const int bx = blockIdx.x;
    const int n  = bx >> 4;
    const int f0 = (bx & 15) * 128;
    const int t  = threadIdx.x;
    const int l  = t & 63;
    const int w  = t >> 6;
    const int l15 = l & 15;
    const int lg  = l >> 4;
    const int wc = (w >> 1) * 64;
    const int wf = (w & 1) * 64;

    // copy W[n, :, :] (128x128 bf16) into LDS
    {
        const int c = t >> 1;
        const int h = (t & 1) * 64;
        const unsigned short* src = W + ((size_t)n * 128 + c) * 128 + h;
#pragma unroll
        for (int j = 0; j < 8; ++j) {
            bf16x8 v = *(const bf16x8*)(src + j * 8);
            *(bf16x8*)&Wl[c * 136 + h + j * 8] = v;
        }
    }

    f32x4 acc[4][4];
#pragma unroll
    for (int i = 0; i < 4; ++i)
#pragma unroll
        for (int j = 0; j < 4; ++j) acc[i][j] = (f32x4)0.0f;

    const int mpr = (t & 15) * 2;    // even m within 32-chunk
    const int fqu = (t >> 4) * 4;    // f quad 0..60

    for (int m0 = 0; m0 < 128; m0 += 32) {
        __syncthreads();             // Wl ready (first) / prev chunk reads done
        // stage X^T chunk: f in [f0,f0+128), m in [m0,m0+32), m-contiguous pairs
#pragma unroll
        for (int pass = 0; pass < 2; ++pass) {
            const int fl = fqu + 64 * pass;
            const float* g = X + ((size_t)n * 128 + m0 + mpr) * 2048 + f0 + fl;
            float4 x0 = *(const float4*)g;
            float4 x1 = *(const float4*)(g + 2048);
            unsigned* Tw = (unsigned*)T;
            Tw[(fl + 0) * 20 + (mpr >> 1)] = f2bf_pk(x0.x, x1.x);
            Tw[(fl + 1) * 20 + (mpr >> 1)] = f2bf_pk(x0.y, x1.y);
            Tw[(fl + 2) * 20 + (mpr >> 1)] = f2bf_pk(x0.z, x1.z);
            Tw[(fl + 3) * 20 + (mpr >> 1)] = f2bf_pk(x0.w, x1.w);
        }
        __syncthreads();
        const int ko = lg * 8;
        bf16x8 a[4], b[4];
#pragma unroll
        for (int i = 0; i < 4; ++i)
            a[i] = *(const bf16x8*)&Wl[(wc + 16 * i + l15) * 136 + m0 + ko];
#pragma unroll
        for (int j = 0; j < 4; ++j)
            b[j] = *(const bf16x8*)&T[(wf + 16 * j + l15) * 40 + ko];
#pragma unroll
        for (int i = 0; i < 4; ++i)
#pragma unroll
            for (int j = 0; j < 4; ++j)
                acc[i][j] = __builtin_amdgcn_mfma_f32_16x16x32_bf16(a[i], b[j], acc[i][j], 0, 0, 0);
    }

#pragma unroll
    for (int i = 0; i < 4; ++i) {
        const int c = wc + 16 * i + lg * 4;
#pragma unroll
        for (int j = 0; j < 4; ++j) {
            const int f = f0 + wf + 16 * j + l15;
            float* o = out + ((size_t)n * 128 + c) * 2048 + f;
#pragma unroll
            for (int r = 0; r < 4; ++r) o[(size_t)r * 2048] = acc[i][j][r];
        }
    }
}

extern "C" void kernel_launch(void* const* d_in, const int* in_sizes, int n_in,
                              void* d_out, int out_size, void* d_ws, size_t ws_size,
                              hipStream_t stream) {
    const float* X = (const float*)d_in[0];   // [64,128,2048]
    const float* A = (const float*)d_in[1];   // [128,128,2048]
    float* out = (float*)d_out;               // [64,128,2048]

    float* part = (float*)d_ws;                                        // 16 MiB
    unsigned short* W = (unsigned short*)((char*)d_ws + WOFF_BYTES);   // 2 MiB bf16

    k_scores<<<dim3(512), dim3(256), 0, stream>>>(X, A, part);
    k_softmax<<<dim3(2048), dim3(256), 0, stream>>>(part, (unsigned int*)W);
    k_combine<<<dim3(1024), dim3(256), 0, stream>>>(X, W, out);
}